// Round 1
// baseline (2655.049 us; speedup 1.0000x reference)
//
#include <hip/hip_runtime.h>
#include <hip/hip_bf16.h>

// GCN: out = (elu(gc(elu(gc(elu(z*),W0,b0)),W1,b1)) concat) @ Wl^T + bl
// gc(x,W,b) = adj @ (x @ W) + b ; adj is 16384^2 fp32 (1 GiB).
//
// v2 strategy: big_gemm is a ZERO-LDS, ZERO-BARRIER direct-to-register MFMA GEMM.
//  - A (adj fp32) loaded straight into fragment regs (16 rows x 128B segments),
//    converted fp32->bf16 in-register (v_cvt_pk_bf16_f32, not the 4-op repack).
//  - B (T, bf16 col-major) fragments are 16B contiguous global loads, L2/L3-served.
//  - K split in 2 halves -> grid 1024 -> 4 blocks/CU, 16 waves/CU for latency
//    hiding without any __syncthreads/vmcnt(0) drain. Partial sums (fp32) are
//    reduced + bias + elu inside the CONSUMER kernels (small_mm / final_mm).
//  - kh = blockIdx&1: round-robin XCD dispatch pins each XCD to one 2 MiB T-half.
// HBM floor: 2 x 1 GiB adj reads ~= 340 us; everything else is L2/L3-resident.

#define NN 16384
#define C2 128   // 2*D_IN
#define DIN 64
#define DOUT 32
#define KHALF 8192

typedef __attribute__((ext_vector_type(8))) __bf16 bf16x8;
typedef __attribute__((ext_vector_type(4))) float f32x4;

__device__ __forceinline__ float eluf(float x) {
    return x > 0.f ? x : __expf(x) - 1.f;
}

__device__ __forceinline__ unsigned short f2bf(float f) {
    unsigned u = __float_as_uint(f);
    u += 0x7FFFu + ((u >> 16) & 1u);   // RNE
    return (unsigned short)(u >> 16);
}

// ---------------------------------------------------------------------------
// small_mm: Tcm[c*NN + r] = sum_k IN(X..)[r, (c>>6)*64 + k] * W[k, c&63]
//   IN = elu(x)              if ELU_IN   (layer-1 input z)
//   IN = elu(p0+p1+bias[k])  if PARTIAL  (layer-2 input from big_gemm partials)
// X: NN x 128 row-major fp32. W: 64x64 row-major fp32. T out bf16 col-major.
template <bool ELU_IN, bool PARTIAL>
__global__ __launch_bounds__(256)
void small_mm(const float* __restrict__ X, const float* __restrict__ X2,
              const float* __restrict__ bias, const float* __restrict__ W,
              unsigned short* __restrict__ Tcm)
{
    __shared__ float WsT[DIN * DIN];   // [c][k] transposed
    const int tid = threadIdx.x;
    for (int i = tid; i < DIN * DIN; i += 256) {
        int c = i >> 6, k = i & 63;
        WsT[i] = W[k * DIN + c];
    }
    __syncthreads();

    const int r     = tid & 63;
    const int chalf = (tid >> 6) & 1;
    const int cq    = tid >> 7;           // 0..1 -> 32 output cols each
    const size_t row = (size_t)blockIdx.x * 64 + r;

    float e[DIN];
    const float* xp  = X + row * C2 + chalf * DIN;
    const float* xp2 = PARTIAL ? (X2 + row * C2 + chalf * DIN) : xp;
#pragma unroll
    for (int i = 0; i < 16; i++) {
        float4 v = ((const float4*)xp)[i];
        if (PARTIAL) {
            float4 v2 = ((const float4*)xp2)[i];
            float4 bv = ((const float4*)bias)[i];   // bias[k], k = i*4+j in [0,64)
            v.x = eluf(v.x + v2.x + bv.x);
            v.y = eluf(v.y + v2.y + bv.y);
            v.z = eluf(v.z + v2.z + bv.z);
            v.w = eluf(v.w + v2.w + bv.w);
        } else if (ELU_IN) {
            v.x = eluf(v.x); v.y = eluf(v.y); v.z = eluf(v.z); v.w = eluf(v.w);
        }
        e[i*4+0] = v.x; e[i*4+1] = v.y; e[i*4+2] = v.z; e[i*4+3] = v.w;
    }

    for (int j = 0; j < 32; j++) {
        int cc = cq * 32 + j;
        const float* wr = WsT + cc * DIN;
        float a = 0.f;
#pragma unroll
        for (int k = 0; k < DIN; k += 4) {
            float4 w = *(const float4*)(wr + k);
            a += e[k]*w.x + e[k+1]*w.y + e[k+2]*w.z + e[k+3]*w.w;
        }
        int c = (chalf << 6) + cc;
        Tcm[(size_t)c * NN + row] = f2bf(a);
    }
}

// ---------------------------------------------------------------------------
// big_gemm: Yp[kh][r,c] = sum_{k in half kh} adj[r,k]*T[k,c]   (fp32, NO bias/elu)
// grid 1024: kh = bid&1 (K half), rb = bid>>1 (32-row tile). block 256 = 4 waves.
// wave w: rows rb*32 + (w&1)*16 .. +16, cols (w>>1)*64 .. +64 (4 B-frags).
// Zero LDS, zero barriers: direct global->reg fragments, 1-step named prefetch.
struct StepRegs { float4 a0, a1; bf16x8 b0, b1, b2, b3; };

__global__ __launch_bounds__(256, 4)
void big_gemm(const float* __restrict__ A, const unsigned short* __restrict__ Bcm,
              float* __restrict__ Yp)
{
    const int bid  = blockIdx.x;
    const int kh   = bid & 1;
    const int rb   = bid >> 1;
    const int tid  = threadIdx.x;
    const int lane = tid & 63;
    const int w    = tid >> 6;
    const int rowg = w & 1;
    const int colg = w >> 1;
    const int m    = lane & 15;
    const int kq   = lane >> 4;

    const size_t kbase = (size_t)kh * KHALF;
    const float* Ap = A + (size_t)(rb * 32 + rowg * 16 + m) * NN + kbase + kq * 8;
    const unsigned short* Bp0 = Bcm + (size_t)(colg * 64 + m) * NN + kbase + kq * 8;
    const unsigned short* Bp1 = Bp0 + (size_t)16 * NN;
    const unsigned short* Bp2 = Bp0 + (size_t)32 * NN;
    const unsigned short* Bp3 = Bp0 + (size_t)48 * NN;

    f32x4 acc0 = {0.f,0.f,0.f,0.f}, acc1 = {0.f,0.f,0.f,0.f};
    f32x4 acc2 = {0.f,0.f,0.f,0.f}, acc3 = {0.f,0.f,0.f,0.f};

    auto load = [&](StepRegs& s, int k) {
        s.a0 = *(const float4*)(Ap + k);
        s.a1 = *(const float4*)(Ap + k + 4);
        s.b0 = *(const bf16x8*)(Bp0 + k);
        s.b1 = *(const bf16x8*)(Bp1 + k);
        s.b2 = *(const bf16x8*)(Bp2 + k);
        s.b3 = *(const bf16x8*)(Bp3 + k);
    };
    auto comp = [&](const StepRegs& s) {
        bf16x8 af;
        af[0] = (__bf16)s.a0.x; af[1] = (__bf16)s.a0.y;
        af[2] = (__bf16)s.a0.z; af[3] = (__bf16)s.a0.w;
        af[4] = (__bf16)s.a1.x; af[5] = (__bf16)s.a1.y;
        af[6] = (__bf16)s.a1.z; af[7] = (__bf16)s.a1.w;
        acc0 = __builtin_amdgcn_mfma_f32_16x16x32_bf16(af, s.b0, acc0, 0, 0, 0);
        acc1 = __builtin_amdgcn_mfma_f32_16x16x32_bf16(af, s.b1, acc1, 0, 0, 0);
        acc2 = __builtin_amdgcn_mfma_f32_16x16x32_bf16(af, s.b2, acc2, 0, 0, 0);
        acc3 = __builtin_amdgcn_mfma_f32_16x16x32_bf16(af, s.b3, acc3, 0, 0, 0);
    };

    StepRegs sA, sB;
    load(sA, 0);
    int k = 0;
    for (int t = 0; t < 127; ++t) {      // 2 K-steps (of 32) per iter, prefetch 1 ahead
        load(sB, k + 32);
        comp(sA);
        load(sA, k + 64);
        comp(sB);
        k += 64;
    }
    load(sB, k + 32);                    // steps 254, 255 (k = 8128, 8160): in-bounds
    comp(sA);
    comp(sB);

    // epilogue: C/D layout col=lane&15, row=(lane>>4)*4+reg ; 16 MiB total, trivial
    float* Yw = Yp + (size_t)kh * NN * C2;
    const int row0 = rb * 32 + rowg * 16 + kq * 4;
    const int col0 = colg * 64 + m;
#pragma unroll
    for (int reg = 0; reg < 4; ++reg) {
        float* yr = Yw + (size_t)(row0 + reg) * C2 + col0;
        yr[0]  = acc0[reg];
        yr[16] = acc1[reg];
        yr[32] = acc2[reg];
        yr[48] = acc3[reg];
    }
}

// ---------------------------------------------------------------------------
// final_mm: out[r,o] = sum_c elu(p0+p1+b1[c&63])[r,c] * Wl[o,c] + bl[o]
__global__ __launch_bounds__(256)
void final_mm(const float* __restrict__ P0, const float* __restrict__ P1,
              const float* __restrict__ b1, const float* __restrict__ Wl,
              const float* __restrict__ bl, float* __restrict__ out)
{
    __shared__ float WlT[C2 * DOUT];     // [c][o]
    __shared__ float red[4 * 64 * 33];   // [cq][r][o] pad 33
    const int tid = threadIdx.x;
    for (int i = tid; i < C2 * DOUT; i += 256) {
        int c = i >> 5, o = i & 31;
        WlT[i] = Wl[o * C2 + c];
    }
    __syncthreads();

    const int r  = tid & 63;
    const int cq = tid >> 6;
    const size_t row = (size_t)blockIdx.x * 64 + r;

    float acc[DOUT];
#pragma unroll
    for (int o = 0; o < DOUT; o++) acc[o] = 0.f;

    const float* yp  = P0 + row * C2 + cq * 32;
    const float* yp2 = P1 + row * C2 + cq * 32;
    const float* bq  = b1 + (cq & 1) * 32;   // bias index (c & 63)
#pragma unroll
    for (int i = 0; i < 8; i++) {
        float4 y  = ((const float4*)yp)[i];
        float4 y2 = ((const float4*)yp2)[i];
        float4 bv = *(const float4*)(bq + i * 4);
        y.x = eluf(y.x + y2.x + bv.x);
        y.y = eluf(y.y + y2.y + bv.y);
        y.z = eluf(y.z + y2.z + bv.z);
        y.w = eluf(y.w + y2.w + bv.w);
        int cb = cq * 32 + i * 4;
#pragma unroll
        for (int o4 = 0; o4 < 8; o4++) {
            float4 w0 = *(const float4*)(WlT + (cb + 0) * DOUT + o4 * 4);
            float4 w1 = *(const float4*)(WlT + (cb + 1) * DOUT + o4 * 4);
            float4 w2 = *(const float4*)(WlT + (cb + 2) * DOUT + o4 * 4);
            float4 w3 = *(const float4*)(WlT + (cb + 3) * DOUT + o4 * 4);
            acc[o4*4+0] += y.x*w0.x + y.y*w1.x + y.z*w2.x + y.w*w3.x;
            acc[o4*4+1] += y.x*w0.y + y.y*w1.y + y.z*w2.y + y.w*w3.y;
            acc[o4*4+2] += y.x*w0.z + y.y*w1.z + y.z*w2.z + y.w*w3.z;
            acc[o4*4+3] += y.x*w0.w + y.y*w1.w + y.z*w2.w + y.w*w3.w;
        }
    }

    float* myred = red + (cq * 64 + r) * 33;
#pragma unroll
    for (int o = 0; o < DOUT; o++) myred[o] = acc[o];
    __syncthreads();

#pragma unroll
    for (int j = 0; j < 8; j++) {
        int id = tid + 256 * j;
        int o  = id & 31;
        int rr = id >> 5;
        float s = bl[o] + red[(0 * 64 + rr) * 33 + o] + red[(1 * 64 + rr) * 33 + o]
                        + red[(2 * 64 + rr) * 33 + o] + red[(3 * 64 + rr) * 33 + o];
        out[((size_t)blockIdx.x * 64 + rr) * DOUT + o] = s;
    }
}

// ---------------------------------------------------------------------------
extern "C" void kernel_launch(void* const* d_in, const int* in_sizes, int n_in,
                              void* d_out, int out_size, void* d_ws, size_t ws_size,
                              hipStream_t stream)
{
    const float* z   = (const float*)d_in[0];
    const float* adj = (const float*)d_in[1];
    const float* W0  = (const float*)d_in[2];
    const float* b0  = (const float*)d_in[3];
    const float* W1  = (const float*)d_in[4];
    const float* b1  = (const float*)d_in[5];
    const float* Wl  = (const float*)d_in[6];
    const float* bl  = (const float*)d_in[7];
    float* out = (float*)d_out;

    // workspace: T (bf16 col-major 128 x NN = 4 MiB) + Yp (2 x fp32 NN x 128 = 16 MiB)
    unsigned short* T = (unsigned short*)d_ws;
    float* Yp  = (float*)((char*)d_ws + (size_t)C2 * NN * sizeof(unsigned short));
    float* Yp0 = Yp;
    float* Yp1 = Yp + (size_t)NN * C2;

    small_mm<true,  false><<<NN / 64, 256, 0, stream>>>(z, nullptr, nullptr, W0, T);
    big_gemm             <<<1024,     256, 0, stream>>>(adj, T, Yp);           // layer-1 partials
    small_mm<false, true ><<<NN / 64, 256, 0, stream>>>(Yp0, Yp1, b0, W1, T);  // T1 = elu(p0+p1+b0)@W1
    big_gemm             <<<1024,     256, 0, stream>>>(adj, T, Yp);           // layer-2 partials
    final_mm             <<<NN / 64, 256, 0, stream>>>(Yp0, Yp1, b1, Wl, bl, out);
}